// Round 1
// baseline (4661.505 us; speedup 1.0000x reference)
//
#include <hip/hip_runtime.h>
#include <cstdint>

// GPT-2-ish forward: B=2, S=2048, E=768, H=12, D=64, FF=3072, L=12, V=32000.
// Strategy: bf16 MFMA GEMMs (fp32 accum), fp32 residual/LN/softmax stats.
// Weights converted fp32->bf16 (transposed to [N][K]) each launch.
// Scratch: big dead-before-logits buffers overlay d_out; emb_bf + x_bf in d_ws.

#define SE 2048
#define EE 768
#define FFD 3072
#define NHEAD 12
#define NLAYER 12
#define MROWS 4096  // B*S

typedef unsigned short u16;
typedef unsigned int u32;
using short8 = __attribute__((ext_vector_type(8))) short;
using f32x4  = __attribute__((ext_vector_type(4))) float;

__device__ __forceinline__ u16 f2bf(float f) {
  union { float f; u32 u; } x; x.f = f;
  u32 r = x.u + 0x7FFFu + ((x.u >> 16) & 1u);
  return (u16)(r >> 16);
}
__device__ __forceinline__ float bf2f(u16 b) {
  union { u32 u; float f; } x; x.u = ((u32)b) << 16;
  return x.f;
}
__device__ __forceinline__ f32x4 mfma16(short8 a, short8 b, f32x4 c) {
  return __builtin_amdgcn_mfma_f32_16x16x32_bf16(a, b, c, 0, 0, 0);
}

// ---------------- weight prep ----------------

// out[c][r] = bf16(in[r][c]); per-layer strides in_ls/out_ls, layer = blockIdx.z
__global__ __launch_bounds__(256) void transpose_convert(
    const float* __restrict__ in, u16* __restrict__ out,
    int R, int C, size_t in_ls, size_t out_ls)
{
  in  += (size_t)blockIdx.z * in_ls;
  out += (size_t)blockIdx.z * out_ls;
  __shared__ float tile[32][33];
  int cx = blockIdx.x * 32, ry = blockIdx.y * 32;
  int c = threadIdx.x & 31, r0 = threadIdx.x >> 5;
#pragma unroll
  for (int i = 0; i < 4; i++) {
    int r = r0 + i * 8;
    tile[r][c] = in[(size_t)(ry + r) * C + cx + c];
  }
  __syncthreads();
#pragma unroll
  for (int i = 0; i < 4; i++) {
    int rr = r0 + i * 8;
    out[(size_t)(cx + rr) * R + ry + c] = f2bf(tile[c][rr]);
  }
}

__global__ __launch_bounds__(256) void convert_bf16(
    const float* __restrict__ in, u16* __restrict__ out)
{
  size_t idx = ((size_t)blockIdx.x * 256 + threadIdx.x) * 4;
  float4 v = *reinterpret_cast<const float4*>(in + idx);
  uint2 o;
  o.x = (u32)f2bf(v.x) | ((u32)f2bf(v.y) << 16);
  o.y = (u32)f2bf(v.z) | ((u32)f2bf(v.w) << 16);
  *reinterpret_cast<uint2*>(out + idx) = o;
}

__global__ __launch_bounds__(256) void rope_table(
    float* __restrict__ cosT, float* __restrict__ sinT)
{
  int idx = blockIdx.x * 256 + threadIdx.x;  // S*32
  int i = idx & 31, s = idx >> 5;
  float freq = powf(10000.f, -(float)i / 32.f);
  float ang = (float)s * freq;
  cosT[idx] = cosf(ang);
  sinT[idx] = sinf(ang);
}

// ---------------- elementwise ----------------

__global__ __launch_bounds__(256) void embed_kernel(
    const int* __restrict__ ids, const float* __restrict__ emb, float* __restrict__ h)
{
  int row = blockIdx.x, t = threadIdx.x;
  size_t src = (size_t)ids[row] * EE;
#pragma unroll
  for (int i = 0; i < 3; i++)
    h[(size_t)row * EE + t + i * 256] = emb[src + t + i * 256];
}

__global__ __launch_bounds__(256) void ln_kernel(
    const float* __restrict__ x, const float* __restrict__ sc,
    const float* __restrict__ bi, u16* __restrict__ out)
{
  int row = blockIdx.x, t = threadIdx.x;
  const float* xr = x + (size_t)row * EE;
  float v[3]; float s = 0.f, ss = 0.f;
#pragma unroll
  for (int i = 0; i < 3; i++) { v[i] = xr[t + i * 256]; s += v[i]; ss += v[i] * v[i]; }
#pragma unroll
  for (int m = 1; m < 64; m <<= 1) { s += __shfl_xor(s, m); ss += __shfl_xor(ss, m); }
  __shared__ float ps[4], pss[4];
  int w = t >> 6;
  if ((t & 63) == 0) { ps[w] = s; pss[w] = ss; }
  __syncthreads();
  s = ps[0] + ps[1] + ps[2] + ps[3];
  ss = pss[0] + pss[1] + pss[2] + pss[3];
  float mu = s * (1.f / 768.f);
  float var = ss * (1.f / 768.f) - mu * mu;
  float rs = rsqrtf(var + 1e-5f);
  u16* orow = out + (size_t)row * EE;
#pragma unroll
  for (int i = 0; i < 3; i++) {
    int c = t + i * 256;
    orow[c] = f2bf((v[i] - mu) * rs * sc[c] + bi[c]);
  }
}

// in-place RoPE on bf16 (B*H, S, D); SCALE also multiplies by 1/8 (=HEAD_DIM^-0.5)
template<bool SCALE>
__global__ __launch_bounds__(256) void rope_apply(
    u16* __restrict__ qk, const float* __restrict__ cosT, const float* __restrict__ sinT)
{
  int idx = blockIdx.x * 256 + threadIdx.x;  // BH*S*32
  int si = idx & 65535;                      // s*32+i
  u32 v = *reinterpret_cast<u32*>(qk + (size_t)idx * 2);
  float xr = bf2f((u16)(v & 0xffff));
  float xi = bf2f((u16)(v >> 16));
  float c = cosT[si], sn = sinT[si];
  float a = xr * c - xi * sn;
  float b = xr * sn + xi * c;
  if (SCALE) { a *= 0.125f; b *= 0.125f; }
  u32 o = (u32)f2bf(a) | ((u32)f2bf(b) << 16);
  *reinterpret_cast<u32*>(qk + (size_t)idx * 2) = o;
}

// ---------------- GEMM: C = A[M][K] @ Bt[N][K]^T ----------------
// MODE 0: bf16 out scattered to qkv[3][B][H][S][D]
// MODE 1: Cf[m][n] += acc (+bias)   (residual accumulate, fp32)
// MODE 2: bf16 out = gelu(acc+bias) (row-major [M][N])
// MODE 3: Cf[m][n] = acc            (fp32 logits)
template<int MODE>
__global__ __launch_bounds__(256) void gemm_bf16(
    const u16* __restrict__ A, const u16* __restrict__ Bt,
    const float* __restrict__ bias, float* __restrict__ Cf, u16* __restrict__ Cb,
    int M, int N, int K)
{
  __shared__ __align__(16) u16 As[128][64];
  __shared__ __align__(16) u16 Bs[128][64];
  const int tid = threadIdx.x;
  const int lane = tid & 63, wave = tid >> 6;
  const int wm = wave >> 1, wn = wave & 1;
  const int lr = lane & 15, lg = lane >> 4;
  const int m0 = blockIdx.y * 128, n0 = blockIdx.x * 128;

  f32x4 acc[4][4] = {};

  for (int k0 = 0; k0 < K; k0 += 64) {
#pragma unroll
    for (int i = 0; i < 4; i++) {
      int cid = tid + i * 256;
      int r = cid >> 3, ch = cid & 7;
      short8 va = *reinterpret_cast<const short8*>(A + (size_t)(m0 + r) * K + k0 + ch * 8);
      *reinterpret_cast<short8*>(&As[r][(ch ^ (r & 7)) << 3]) = va;
      short8 vb = *reinterpret_cast<const short8*>(Bt + (size_t)(n0 + r) * K + k0 + ch * 8);
      *reinterpret_cast<short8*>(&Bs[r][(ch ^ (r & 7)) << 3]) = vb;
    }
    __syncthreads();
    short8 af[2][4], bfr[2][4];
#pragma unroll
    for (int kk = 0; kk < 2; kk++) {
#pragma unroll
      for (int mi = 0; mi < 4; mi++) {
        int r = wm * 64 + mi * 16 + lr;
        af[kk][mi] = *reinterpret_cast<const short8*>(&As[r][(((kk * 4 + lg) ^ (r & 7)) << 3)]);
      }
#pragma unroll
      for (int ni = 0; ni < 4; ni++) {
        int r = wn * 64 + ni * 16 + lr;
        bfr[kk][ni] = *reinterpret_cast<const short8*>(&Bs[r][(((kk * 4 + lg) ^ (r & 7)) << 3)]);
      }
    }
#pragma unroll
    for (int kk = 0; kk < 2; kk++)
#pragma unroll
      for (int mi = 0; mi < 4; mi++)
#pragma unroll
        for (int ni = 0; ni < 4; ni++)
          acc[mi][ni] = mfma16(af[kk][mi], bfr[kk][ni], acc[mi][ni]);
    __syncthreads();
  }

#pragma unroll
  for (int mi = 0; mi < 4; mi++)
#pragma unroll
    for (int ni = 0; ni < 4; ni++) {
      int row0 = m0 + wm * 64 + mi * 16 + lg * 4;
      int col  = n0 + wn * 64 + ni * 16 + lr;
#pragma unroll
      for (int r2 = 0; r2 < 4; r2++) {
        float v = acc[mi][ni][r2];
        int row = row0 + r2;
        if constexpr (MODE == 1) {
          if (bias) v += bias[col];
          Cf[(size_t)row * N + col] += v;
        } else if constexpr (MODE == 3) {
          Cf[(size_t)row * N + col] = v;
        } else if constexpr (MODE == 2) {
          v += bias[col];
          float z = 0.7978845608f * (v + 0.044715f * v * v * v);
          float g = 0.5f * v * (1.f + tanhf(z));
          Cb[(size_t)row * N + col] = f2bf(g);
        } else {  // MODE 0: scatter to qkv[3][2][12][2048][64]
          int which = col / 768;
          int nh = col - which * 768;
          int hh = nh >> 6, d = nh & 63;
          int b = row >> 11, s = row & 2047;
          Cb[((((size_t)which * 2 + b) * 12 + hh) * 2048 + s) * 64 + d] = f2bf(v);
        }
      }
    }
}

// ---------------- flash attention (non-causal, full softmax) ----------------
// grid: (S/64, B*H); 4 waves, each owns 16 q-rows. K/V tiles of 64 staged in LDS.
__global__ __launch_bounds__(256) void attn_kernel(
    const u16* __restrict__ Q, const u16* __restrict__ Kb,
    const u16* __restrict__ Vb, u16* __restrict__ O)
{
  __shared__ __align__(16) u16 Ks[64][64];
  __shared__ __align__(16) u16 Vt[64][64];      // [d][k], swizzled
  __shared__ __align__(16) u16 Ps[4][16][64];   // per-wave P tile
  const int tid = threadIdx.x;
  const int lane = tid & 63, wave = tid >> 6;
  const int lr = lane & 15, lg = lane >> 4;
  const int bh = blockIdx.y;
  const int q0 = blockIdx.x * 64 + wave * 16;
  const size_t base = (size_t)bh * SE * 64;

  short8 qf[2];
#pragma unroll
  for (int kk = 0; kk < 2; kk++)
    qf[kk] = *reinterpret_cast<const short8*>(Q + base + (size_t)(q0 + lr) * 64 + kk * 32 + lg * 8);

  f32x4 accO[4] = {};
  float mrow[4], lsum[4];
#pragma unroll
  for (int r = 0; r < 4; r++) { mrow[r] = -1e30f; lsum[r] = 0.f; }

  for (int kt = 0; kt < SE / 64; kt++) {
    __syncthreads();
#pragma unroll
    for (int i = 0; i < 2; i++) {
      int cid = tid + i * 256;
      int r = cid >> 3, ch = cid & 7;
      short8 v = *reinterpret_cast<const short8*>(Kb + base + (size_t)(kt * 64 + r) * 64 + ch * 8);
      *reinterpret_cast<short8*>(&Ks[r][(ch ^ (r & 7)) << 3]) = v;
      short8 vv = *reinterpret_cast<const short8*>(Vb + base + (size_t)(kt * 64 + r) * 64 + ch * 8);
#pragma unroll
      for (int j = 0; j < 8; j++) {
        int d = ch * 8 + j;
        Vt[d][((((r >> 3) ^ (d & 7)) << 3) | (r & 7))] = (u16)vv[j];
      }
    }
    __syncthreads();

    f32x4 s4[4];
#pragma unroll
    for (int ni = 0; ni < 4; ni++) {
      f32x4 a = {};
      int r = ni * 16 + lr;
#pragma unroll
      for (int kk = 0; kk < 2; kk++) {
        short8 kf = *reinterpret_cast<const short8*>(&Ks[r][(((kk * 4 + lg) ^ (r & 7)) << 3)]);
        a = mfma16(qf[kk], kf, a);
      }
      s4[ni] = a;
    }
#pragma unroll
    for (int r = 0; r < 4; r++) {
      float mx = fmaxf(fmaxf(s4[0][r], s4[1][r]), fmaxf(s4[2][r], s4[3][r]));
#pragma unroll
      for (int m = 1; m < 16; m <<= 1) mx = fmaxf(mx, __shfl_xor(mx, m));
      float mnew = fmaxf(mrow[r], mx);
      float corr = __expf(mrow[r] - mnew);
      float psum = 0.f;
#pragma unroll
      for (int ni = 0; ni < 4; ni++) {
        float p = __expf(s4[ni][r] - mnew);
        s4[ni][r] = p;
        psum += p;
      }
#pragma unroll
      for (int m = 1; m < 16; m <<= 1) psum += __shfl_xor(psum, m);
      lsum[r] = lsum[r] * corr + psum;
      mrow[r] = mnew;
#pragma unroll
      for (int ni = 0; ni < 4; ni++) accO[ni][r] *= corr;
    }
#pragma unroll
    for (int ni = 0; ni < 4; ni++)
#pragma unroll
      for (int r = 0; r < 4; r++) {
        int prow = lg * 4 + r;
        int col = ni * 16 + lr;
        Ps[wave][prow][((col & 7) | (((col >> 3) ^ (prow & 7)) << 3))] = f2bf(s4[ni][r]);
      }
#pragma unroll
    for (int ni = 0; ni < 4; ni++) {
#pragma unroll
      for (int kk = 0; kk < 2; kk++) {
        short8 pf = *reinterpret_cast<const short8*>(&Ps[wave][lr][(((kk * 4 + lg) ^ (lr & 7)) << 3)]);
        int vrow = ni * 16 + lr;
        short8 vf = *reinterpret_cast<const short8*>(&Vt[vrow][(((kk * 4 + lg) ^ (vrow & 7)) << 3)]);
        accO[ni] = mfma16(pf, vf, accO[ni]);
      }
    }
  }
  const int b = bh / 12, hh = bh % 12;
#pragma unroll
  for (int ni = 0; ni < 4; ni++)
#pragma unroll
    for (int r = 0; r < 4; r++) {
      int s = q0 + lg * 4 + r;
      int d = ni * 16 + lr;
      O[((size_t)(b * SE + s)) * EE + hh * 64 + d] = f2bf(accO[ni][r] / lsum[r]);
    }
}

// ---------------- host orchestration ----------------

extern "C" void kernel_launch(void* const* d_in, const int* in_sizes, int n_in,
                              void* d_out, int out_size, void* d_ws, size_t ws_size,
                              hipStream_t stream) {
  const int*   ids  = (const int*)d_in[0];
  const float* emb  = (const float*)d_in[1];
  const float* qw   = (const float*)d_in[2];
  const float* kw   = (const float*)d_in[3];
  const float* vw   = (const float*)d_in[4];
  const float* ow   = (const float*)d_in[5];
  const float* w1   = (const float*)d_in[6];
  const float* b1   = (const float*)d_in[7];
  const float* w2   = (const float*)d_in[8];
  const float* b2   = (const float*)d_in[9];
  const float* ln1s = (const float*)d_in[10];
  const float* ln1b = (const float*)d_in[11];
  const float* ln2s = (const float*)d_in[12];
  const float* ln2b = (const float*)d_in[13];
  const float* lnfs = (const float*)d_in[14];
  const float* lnfb = (const float*)d_in[15];

  // scratch overlay on d_out (524,288,000 B); all regions dead before logits GEMM
  char* oc = (char*)d_out;
  u16*   wqkv_t = (u16*)(oc + 0);            // 42,467,328 B : [L][3][E][E] (Bt)
  u16*   wo_t   = (u16*)(oc + 42467328);     // 14,155,776 B : [L][E][E]
  u16*   w1_t   = (u16*)(oc + 56623104);     // 56,623,104 B : [L][FF][E]
  u16*   w2_t   = (u16*)(oc + 113246208);    // 56,623,104 B : [L][E][FF]
  float* h      = (float*)(oc + 169869312);  // 12,582,912 B : residual fp32
  u16*   qkv_bf = (u16*)(oc + 182452224);    // 18,874,368 B : [3][B][H][S][D]
  u16*   o_bf   = (u16*)(oc + 201326592);    //  6,291,456 B : [M][E]
  u16*   mid_bf = (u16*)(oc + 207618048);    // 25,165,824 B : [M][FF]
  float* cosT   = (float*)(oc + 232783872);  //    262,144 B
  float* sinT   = (float*)(oc + 233046016);  //    262,144 B
  // ws: buffers read by the logits GEMM (can't overlay d_out)
  u16*   emb_bf = (u16*)d_ws;                           // 49,152,000 B : [V][E]
  u16*   x_bf   = (u16*)((char*)d_ws + 49152000);       //  6,291,456 B : [M][E]
  float* logits = (float*)d_out;

  dim3 blk(256);
  const size_t EE2 = (size_t)EE * EE;

  // weight prep
  transpose_convert<<<dim3(24, 24, 12), blk, 0, stream>>>(qw, wqkv_t,           EE, EE, EE2, 3 * EE2);
  transpose_convert<<<dim3(24, 24, 12), blk, 0, stream>>>(kw, wqkv_t + EE2,     EE, EE, EE2, 3 * EE2);
  transpose_convert<<<dim3(24, 24, 12), blk, 0, stream>>>(vw, wqkv_t + 2 * EE2, EE, EE, EE2, 3 * EE2);
  transpose_convert<<<dim3(24, 24, 12), blk, 0, stream>>>(ow, wo_t, EE, EE, EE2, EE2);
  transpose_convert<<<dim3(96, 24, 12), blk, 0, stream>>>(w1, w1_t, EE, FFD, (size_t)EE * FFD, (size_t)EE * FFD);
  transpose_convert<<<dim3(24, 96, 12), blk, 0, stream>>>(w2, w2_t, FFD, EE, (size_t)EE * FFD, (size_t)EE * FFD);
  convert_bf16<<<24000, blk, 0, stream>>>(emb, emb_bf);
  rope_table<<<256, blk, 0, stream>>>(cosT, sinT);
  embed_kernel<<<4096, blk, 0, stream>>>(ids, emb, h);

  const size_t HSD = (size_t)24 * SE * 64;  // 3,145,728 elems per q/k/v block

  for (int l = 0; l < NLAYER; l++) {
    ln_kernel<<<4096, blk, 0, stream>>>(h, ln1s + l * EE, ln1b + l * EE, x_bf);
    gemm_bf16<0><<<dim3(18, 32), blk, 0, stream>>>(x_bf, wqkv_t + (size_t)l * 3 * EE2,
                                                   nullptr, nullptr, qkv_bf, MROWS, 3 * EE, EE);
    rope_apply<true ><<<6144, blk, 0, stream>>>(qkv_bf,       cosT, sinT);
    rope_apply<false><<<6144, blk, 0, stream>>>(qkv_bf + HSD, cosT, sinT);
    attn_kernel<<<dim3(32, 24), blk, 0, stream>>>(qkv_bf, qkv_bf + HSD, qkv_bf + 2 * HSD, o_bf);
    gemm_bf16<1><<<dim3(6, 32), blk, 0, stream>>>(o_bf, wo_t + (size_t)l * EE2,
                                                  nullptr, h, nullptr, MROWS, EE, EE);
    ln_kernel<<<4096, blk, 0, stream>>>(h, ln2s + l * EE, ln2b + l * EE, x_bf);
    gemm_bf16<2><<<dim3(24, 32), blk, 0, stream>>>(x_bf, w1_t + (size_t)l * EE * FFD,
                                                   b1 + (size_t)l * FFD, nullptr, mid_bf, MROWS, FFD, EE);
    gemm_bf16<1><<<dim3(6, 32), blk, 0, stream>>>(mid_bf, w2_t + (size_t)l * EE * FFD,
                                                  b2 + (size_t)l * EE, h, nullptr, MROWS, EE, FFD);
  }
  ln_kernel<<<4096, blk, 0, stream>>>(h, lnfs, lnfb, x_bf);
  gemm_bf16<3><<<dim3(250, 32), blk, 0, stream>>>(x_bf, emb_bf, nullptr, logits, nullptr,
                                                  MROWS, 32000, EE);
}

// Round 2
// 4334.938 us; speedup vs baseline: 1.0753x; 1.0753x over previous
//
#include <hip/hip_runtime.h>
#include <cstdint>

// GPT-2-ish forward: B=2, S=2048, E=768, H=12, D=64, FF=3072, L=12, V=32000.
// bf16 MFMA GEMMs (fp32 accum), fp32 residual/LN/softmax stats.
// R2: global_load_lds staging (pre-swizzled source), M-fast logits order,
//     attn KVBLK=128 + V transposed in QKV-GEMM epilogue + defer-max.

#define SE 2048
#define EE 768
#define FFD 3072
#define NLAYER 12
#define MROWS 4096
#define HSD_C 3145728  // 24*2048*64

typedef unsigned short u16;
typedef unsigned int u32;
using short8 = __attribute__((ext_vector_type(8))) short;
using f32x4  = __attribute__((ext_vector_type(4))) float;

__device__ __forceinline__ u16 f2bf(float f) {
  union { float f; u32 u; } x; x.f = f;
  u32 r = x.u + 0x7FFFu + ((x.u >> 16) & 1u);
  return (u16)(r >> 16);
}
__device__ __forceinline__ float bf2f(u16 b) {
  union { u32 u; float f; } x; x.u = ((u32)b) << 16;
  return x.f;
}
__device__ __forceinline__ f32x4 mfma16(short8 a, short8 b, f32x4 c) {
  return __builtin_amdgcn_mfma_f32_16x16x32_bf16(a, b, c, 0, 0, 0);
}
// async global->LDS, 16B per lane; dest = wave-uniform base + lane*16
__device__ __forceinline__ void gload16(const u16* g, u16* l) {
  __builtin_amdgcn_global_load_lds(
      (const __attribute__((address_space(1))) u32*)g,
      (__attribute__((address_space(3))) u32*)l, 16, 0, 0);
}

// ---------------- weight prep ----------------

__global__ __launch_bounds__(256) void transpose_convert(
    const float* __restrict__ in, u16* __restrict__ out,
    int R, int C, size_t in_ls, size_t out_ls)
{
  in  += (size_t)blockIdx.z * in_ls;
  out += (size_t)blockIdx.z * out_ls;
  __shared__ float tile[32][33];
  int cx = blockIdx.x * 32, ry = blockIdx.y * 32;
  int c = threadIdx.x & 31, r0 = threadIdx.x >> 5;
#pragma unroll
  for (int i = 0; i < 4; i++) {
    int r = r0 + i * 8;
    tile[r][c] = in[(size_t)(ry + r) * C + cx + c];
  }
  __syncthreads();
#pragma unroll
  for (int i = 0; i < 4; i++) {
    int rr = r0 + i * 8;
    out[(size_t)(cx + rr) * R + ry + c] = f2bf(tile[c][rr]);
  }
}

__global__ __launch_bounds__(256) void convert_bf16(
    const float* __restrict__ in, u16* __restrict__ out)
{
  size_t idx = ((size_t)blockIdx.x * 256 + threadIdx.x) * 4;
  float4 v = *reinterpret_cast<const float4*>(in + idx);
  uint2 o;
  o.x = (u32)f2bf(v.x) | ((u32)f2bf(v.y) << 16);
  o.y = (u32)f2bf(v.z) | ((u32)f2bf(v.w) << 16);
  *reinterpret_cast<uint2*>(out + idx) = o;
}

__global__ __launch_bounds__(256) void rope_table(
    float* __restrict__ cosT, float* __restrict__ sinT)
{
  int idx = blockIdx.x * 256 + threadIdx.x;  // S*32
  int i = idx & 31, s = idx >> 5;
  float freq = powf(10000.f, -(float)i / 32.f);
  float ang = (float)s * freq;
  cosT[idx] = cosf(ang);
  sinT[idx] = sinf(ang);
}

// ---------------- elementwise ----------------

__global__ __launch_bounds__(256) void embed_kernel(
    const int* __restrict__ ids, const float* __restrict__ emb, float* __restrict__ h)
{
  int row = blockIdx.x, t = threadIdx.x;
  size_t src = (size_t)ids[row] * EE;
#pragma unroll
  for (int i = 0; i < 3; i++)
    h[(size_t)row * EE + t + i * 256] = emb[src + t + i * 256];
}

__global__ __launch_bounds__(256) void ln_kernel(
    const float* __restrict__ x, const float* __restrict__ sc,
    const float* __restrict__ bi, u16* __restrict__ out)
{
  int row = blockIdx.x, t = threadIdx.x;
  const float* xr = x + (size_t)row * EE;
  float v[3]; float s = 0.f, ss = 0.f;
#pragma unroll
  for (int i = 0; i < 3; i++) { v[i] = xr[t + i * 256]; s += v[i]; ss += v[i] * v[i]; }
#pragma unroll
  for (int m = 1; m < 64; m <<= 1) { s += __shfl_xor(s, m); ss += __shfl_xor(ss, m); }
  __shared__ float ps[4], pss[4];
  int w = t >> 6;
  if ((t & 63) == 0) { ps[w] = s; pss[w] = ss; }
  __syncthreads();
  s = ps[0] + ps[1] + ps[2] + ps[3];
  ss = pss[0] + pss[1] + pss[2] + pss[3];
  float mu = s * (1.f / 768.f);
  float var = ss * (1.f / 768.f) - mu * mu;
  float rs = rsqrtf(var + 1e-5f);
  u16* orow = out + (size_t)row * EE;
#pragma unroll
  for (int i = 0; i < 3; i++) {
    int c = t + i * 256;
    orow[c] = f2bf((v[i] - mu) * rs * sc[c] + bi[c]);
  }
}

template<bool SCALE>
__global__ __launch_bounds__(256) void rope_apply(
    u16* __restrict__ qk, const float* __restrict__ cosT, const float* __restrict__ sinT)
{
  int idx = blockIdx.x * 256 + threadIdx.x;  // BH*S*32
  int si = idx & 65535;                      // s*32+i
  u32 v = *reinterpret_cast<u32*>(qk + (size_t)idx * 2);
  float xr = bf2f((u16)(v & 0xffff));
  float xi = bf2f((u16)(v >> 16));
  float c = cosT[si], sn = sinT[si];
  float a = xr * c - xi * sn;
  float b = xr * sn + xi * c;
  if (SCALE) { a *= 0.125f; b *= 0.125f; }
  u32 o = (u32)f2bf(a) | ((u32)f2bf(b) << 16);
  *reinterpret_cast<u32*>(qk + (size_t)idx * 2) = o;
}

// ---------------- GEMM: C = A[M][K] @ Bt[N][K]^T ----------------
// MODE 0: bf16 out scattered to qkv; V block-cols written TRANSPOSED [bh][d][s]
// MODE 1: Cf[m][n] += acc (+bias)
// MODE 2: bf16 out = gelu(acc+bias)
// MODE 3: Cf[m][n] = acc (logits; grid x=M-tiles for B-panel L2 reuse)
template<int MODE>
__global__ __launch_bounds__(256) void gemm_bf16(
    const u16* __restrict__ A, const u16* __restrict__ Bt,
    const float* __restrict__ bias, float* __restrict__ Cf, u16* __restrict__ Cb,
    int M, int N, int K)
{
  __shared__ __align__(16) u16 As[128][64];
  __shared__ __align__(16) u16 Bs[128][64];
  const int tid = threadIdx.x;
  const int lane = tid & 63, wave = tid >> 6;
  const int wm = wave >> 1, wn = wave & 1;
  const int lr = lane & 15, lg = lane >> 4;
  int bx, by;
  if constexpr (MODE == 3) { bx = blockIdx.y; by = blockIdx.x; }
  else { bx = blockIdx.x; by = blockIdx.y; }
  const int m0 = by * 128, n0 = bx * 128;
  const int srs = lane >> 3, scs = lane & 7;  // staging row-offset / lds-chunk

  f32x4 acc[4][4] = {};

  for (int k0 = 0; k0 < K; k0 += 64) {
#pragma unroll
    for (int i = 0; i < 4; i++) {
      int rb = wave * 32 + i * 8;
      int r = rb + srs;
      int chs = scs ^ (r & 7);
      gload16(A  + (size_t)(m0 + r) * K + k0 + chs * 8, &As[rb][0]);
      gload16(Bt + (size_t)(n0 + r) * K + k0 + chs * 8, &Bs[rb][0]);
    }
    __syncthreads();
    short8 af[2][4], bfr[2][4];
#pragma unroll
    for (int kk = 0; kk < 2; kk++) {
#pragma unroll
      for (int mi = 0; mi < 4; mi++) {
        int r = wm * 64 + mi * 16 + lr;
        af[kk][mi] = *reinterpret_cast<const short8*>(&As[r][(((kk * 4 + lg) ^ (r & 7)) << 3)]);
      }
#pragma unroll
      for (int ni = 0; ni < 4; ni++) {
        int r = wn * 64 + ni * 16 + lr;
        bfr[kk][ni] = *reinterpret_cast<const short8*>(&Bs[r][(((kk * 4 + lg) ^ (r & 7)) << 3)]);
      }
    }
#pragma unroll
    for (int kk = 0; kk < 2; kk++)
#pragma unroll
      for (int mi = 0; mi < 4; mi++)
#pragma unroll
        for (int ni = 0; ni < 4; ni++)
          acc[mi][ni] = mfma16(af[kk][mi], bfr[kk][ni], acc[mi][ni]);
    __syncthreads();
  }

#pragma unroll
  for (int mi = 0; mi < 4; mi++)
#pragma unroll
    for (int ni = 0; ni < 4; ni++) {
      int row0 = m0 + wm * 64 + mi * 16 + lg * 4;
      int col  = n0 + wn * 64 + ni * 16 + lr;
      if constexpr (MODE == 0) {
        int b = row0 >> 11, s0 = row0 & 2047;
        if (n0 >= 1536) {  // V: write transposed [b][h][d][s]
          int nh = col - 1536;
          int hh = nh >> 6, d = nh & 63;
          uint2 pk;
          pk.x = (u32)f2bf(acc[mi][ni][0]) | ((u32)f2bf(acc[mi][ni][1]) << 16);
          pk.y = (u32)f2bf(acc[mi][ni][2]) | ((u32)f2bf(acc[mi][ni][3]) << 16);
          *reinterpret_cast<uint2*>(
              &Cb[(size_t)2 * HSD_C + ((size_t)((b * 12 + hh) * 64 + d)) * 2048 + s0]) = pk;
        } else {           // Q/K: [which][b][h][s][d]
          int which = col >= 768 ? 1 : 0;
          int nh = col - which * 768;
          int hh = nh >> 6, d = nh & 63;
#pragma unroll
          for (int r2 = 0; r2 < 4; r2++)
            Cb[((((size_t)which * 2 + b) * 12 + hh) * 2048 + (s0 + r2)) * 64 + d] =
                f2bf(acc[mi][ni][r2]);
        }
      } else {
#pragma unroll
        for (int r2 = 0; r2 < 4; r2++) {
          float v = acc[mi][ni][r2];
          int row = row0 + r2;
          if constexpr (MODE == 1) {
            if (bias) v += bias[col];
            Cf[(size_t)row * N + col] += v;
          } else if constexpr (MODE == 3) {
            Cf[(size_t)row * N + col] = v;
          } else {  // MODE 2: gelu = v*sigmoid(2z)
            v += bias[col];
            float z = 0.7978845608f * (v + 0.044715f * v * v * v);
            float g = v / (1.f + __expf(-2.f * z));
            Cb[(size_t)row * N + col] = f2bf(g);
          }
        }
      }
    }
}

// ---------------- flash attention (non-causal), KVBLK=128 ----------------
// grid (S/64, B*H); 4 waves * 16 q-rows. K [128][64] + Vt [64][128] in LDS.
__global__ __launch_bounds__(256) void attn_kernel(
    const u16* __restrict__ Q, const u16* __restrict__ Kb,
    const u16* __restrict__ Vt, u16* __restrict__ O)
{
  __shared__ __align__(16) u16 Ks[128][64];
  __shared__ __align__(16) u16 Vs[64][128];
  __shared__ __align__(16) u16 Ps[4][16][128];
  const int tid = threadIdx.x;
  const int lane = tid & 63, wave = tid >> 6;
  const int lr = lane & 15, lg = lane >> 4;
  const int bh = blockIdx.y;
  const int q0 = blockIdx.x * 64 + wave * 16;
  const size_t baseK = (size_t)bh * SE * 64;
  const size_t baseV = (size_t)bh * 64 * SE;
  const int krs = lane >> 3, kcs = lane & 7;
  const int vrs = lane >> 4, vcs = lane & 15;

  short8 qf[2];
#pragma unroll
  for (int kk = 0; kk < 2; kk++)
    qf[kk] = *reinterpret_cast<const short8*>(Q + baseK + (size_t)(q0 + lr) * 64 + kk * 32 + lg * 8);

  f32x4 accO[4] = {};
  float mrow[4], lsum[4];
#pragma unroll
  for (int r = 0; r < 4; r++) { mrow[r] = -1e30f; lsum[r] = 0.f; }

  for (int kt = 0; kt < SE / 128; kt++) {
    __syncthreads();
#pragma unroll
    for (int i = 0; i < 4; i++) {
      int rb = wave * 32 + i * 8;
      int r = rb + krs;
      int chs = kcs ^ (r & 7);
      gload16(Kb + baseK + (size_t)(kt * 128 + r) * 64 + chs * 8, &Ks[rb][0]);
    }
#pragma unroll
    for (int i = 0; i < 4; i++) {
      int rb = wave * 16 + i * 4;
      int r = rb + vrs;
      int chs = vcs ^ (r & 15);
      gload16(Vt + baseV + (size_t)r * SE + kt * 128 + chs * 8, &Vs[rb][0]);
    }
    __syncthreads();

    f32x4 s4[8];
#pragma unroll
    for (int ni = 0; ni < 8; ni++) {
      f32x4 a = {};
      int r = ni * 16 + lr;
#pragma unroll
      for (int kk = 0; kk < 2; kk++) {
        short8 kf = *reinterpret_cast<const short8*>(&Ks[r][(((kk * 4 + lg) ^ (r & 7)) << 3)]);
        a = mfma16(qf[kk], kf, a);
      }
      s4[ni] = a;
    }
#pragma unroll
    for (int r2 = 0; r2 < 4; r2++) {
      float mx = s4[0][r2];
#pragma unroll
      for (int ni = 1; ni < 8; ni++) mx = fmaxf(mx, s4[ni][r2]);
#pragma unroll
      for (int m = 1; m < 16; m <<= 1) mx = fmaxf(mx, __shfl_xor(mx, m));
      if (mx > mrow[r2] + 8.f) {  // defer-max (T13): P bounded by e^8
        float corr = __expf(mrow[r2] - mx);
        mrow[r2] = mx;
        lsum[r2] *= corr;
#pragma unroll
        for (int ni = 0; ni < 4; ni++) accO[ni][r2] *= corr;
      }
      float psum = 0.f;
#pragma unroll
      for (int ni = 0; ni < 8; ni++) {
        float p = __expf(s4[ni][r2] - mrow[r2]);
        s4[ni][r2] = p;
        psum += p;
      }
#pragma unroll
      for (int m = 1; m < 16; m <<= 1) psum += __shfl_xor(psum, m);
      lsum[r2] += psum;
    }
#pragma unroll
    for (int ni = 0; ni < 8; ni++)
#pragma unroll
      for (int r2 = 0; r2 < 4; r2++) {
        int q = lg * 4 + r2;
        int k = ni * 16 + lr;
        Ps[wave][q][(((k >> 3) ^ q) << 3) | (k & 7)] = f2bf(s4[ni][r2]);
      }
#pragma unroll
    for (int kk = 0; kk < 4; kk++) {
      short8 pf = *reinterpret_cast<const short8*>(&Ps[wave][lr][(((kk * 4 + lg) ^ lr) << 3)]);
#pragma unroll
      for (int ni = 0; ni < 4; ni++) {
        int r = ni * 16 + lr;
        short8 vf = *reinterpret_cast<const short8*>(&Vs[r][(((kk * 4 + lg) ^ (r & 15)) << 3)]);
        accO[ni] = mfma16(pf, vf, accO[ni]);
      }
    }
  }
  const int b = bh / 12, hh = bh % 12;
#pragma unroll
  for (int ni = 0; ni < 4; ni++)
#pragma unroll
    for (int r = 0; r < 4; r++) {
      int s = q0 + lg * 4 + r;
      int d = ni * 16 + lr;
      O[((size_t)(b * SE + s)) * EE + hh * 64 + d] = f2bf(accO[ni][r] / lsum[r]);
    }
}

// ---------------- host orchestration ----------------

extern "C" void kernel_launch(void* const* d_in, const int* in_sizes, int n_in,
                              void* d_out, int out_size, void* d_ws, size_t ws_size,
                              hipStream_t stream) {
  const int*   ids  = (const int*)d_in[0];
  const float* emb  = (const float*)d_in[1];
  const float* qw   = (const float*)d_in[2];
  const float* kw   = (const float*)d_in[3];
  const float* vw   = (const float*)d_in[4];
  const float* ow   = (const float*)d_in[5];
  const float* w1   = (const float*)d_in[6];
  const float* b1   = (const float*)d_in[7];
  const float* w2   = (const float*)d_in[8];
  const float* b2   = (const float*)d_in[9];
  const float* ln1s = (const float*)d_in[10];
  const float* ln1b = (const float*)d_in[11];
  const float* ln2s = (const float*)d_in[12];
  const float* ln2b = (const float*)d_in[13];
  const float* lnfs = (const float*)d_in[14];
  const float* lnfb = (const float*)d_in[15];

  char* oc = (char*)d_out;
  u16*   wqkv_t = (u16*)(oc + 0);            // [L][3][E][E]
  u16*   wo_t   = (u16*)(oc + 42467328);     // [L][E][E]
  u16*   w1_t   = (u16*)(oc + 56623104);     // [L][FF][E]
  u16*   w2_t   = (u16*)(oc + 113246208);    // [L][E][FF]
  float* h      = (float*)(oc + 169869312);  // residual fp32
  u16*   qkv_bf = (u16*)(oc + 182452224);    // Q,K:[2][B][H][S][D]; V:[B][H][D][S]
  u16*   o_bf   = (u16*)(oc + 201326592);    // [M][E]
  u16*   mid_bf = (u16*)(oc + 207618048);    // [M][FF]
  float* cosT   = (float*)(oc + 232783872);
  float* sinT   = (float*)(oc + 233046016);
  u16*   emb_bf = (u16*)d_ws;                           // [V][E]
  u16*   x_bf   = (u16*)((char*)d_ws + 49152000);       // [M][E]
  float* logits = (float*)d_out;

  dim3 blk(256);
  const size_t EE2 = (size_t)EE * EE;

  transpose_convert<<<dim3(24, 24, 12), blk, 0, stream>>>(qw, wqkv_t,           EE, EE, EE2, 3 * EE2);
  transpose_convert<<<dim3(24, 24, 12), blk, 0, stream>>>(kw, wqkv_t + EE2,     EE, EE, EE2, 3 * EE2);
  transpose_convert<<<dim3(24, 24, 12), blk, 0, stream>>>(vw, wqkv_t + 2 * EE2, EE, EE, EE2, 3 * EE2);
  transpose_convert<<<dim3(24, 24, 12), blk, 0, stream>>>(ow, wo_t, EE, EE, EE2, EE2);
  transpose_convert<<<dim3(96, 24, 12), blk, 0, stream>>>(w1, w1_t, EE, FFD, (size_t)EE * FFD, (size_t)EE * FFD);
  transpose_convert<<<dim3(24, 96, 12), blk, 0, stream>>>(w2, w2_t, FFD, EE, (size_t)EE * FFD, (size_t)EE * FFD);
  convert_bf16<<<24000, blk, 0, stream>>>(emb, emb_bf);
  rope_table<<<256, blk, 0, stream>>>(cosT, sinT);
  embed_kernel<<<4096, blk, 0, stream>>>(ids, emb, h);

  const size_t HSD = (size_t)HSD_C;

  for (int l = 0; l < NLAYER; l++) {
    ln_kernel<<<4096, blk, 0, stream>>>(h, ln1s + l * EE, ln1b + l * EE, x_bf);
    gemm_bf16<0><<<dim3(18, 32), blk, 0, stream>>>(x_bf, wqkv_t + (size_t)l * 3 * EE2,
                                                   nullptr, nullptr, qkv_bf, MROWS, 3 * EE, EE);
    rope_apply<true ><<<6144, blk, 0, stream>>>(qkv_bf,       cosT, sinT);
    rope_apply<false><<<6144, blk, 0, stream>>>(qkv_bf + HSD, cosT, sinT);
    attn_kernel<<<dim3(32, 24), blk, 0, stream>>>(qkv_bf, qkv_bf + HSD, qkv_bf + 2 * HSD, o_bf);
    gemm_bf16<1><<<dim3(6, 32), blk, 0, stream>>>(o_bf, wo_t + (size_t)l * EE2,
                                                  nullptr, h, nullptr, MROWS, EE, EE);
    ln_kernel<<<4096, blk, 0, stream>>>(h, ln2s + l * EE, ln2b + l * EE, x_bf);
    gemm_bf16<2><<<dim3(24, 32), blk, 0, stream>>>(x_bf, w1_t + (size_t)l * EE * FFD,
                                                   b1 + (size_t)l * FFD, nullptr, mid_bf, MROWS, FFD, EE);
    gemm_bf16<1><<<dim3(6, 32), blk, 0, stream>>>(mid_bf, w2_t + (size_t)l * EE * FFD,
                                                  b2 + (size_t)l * EE, h, nullptr, MROWS, EE, FFD);
  }
  ln_kernel<<<4096, blk, 0, stream>>>(h, lnfs, lnfb, x_bf);
  gemm_bf16<3><<<dim3(32, 250), blk, 0, stream>>>(x_bf, emb_bf, nullptr, logits, nullptr,
                                                  MROWS, 32000, EE);
}